// Round 10
// baseline (369.737 us; speedup 1.0000x reference)
//
#include <hip/hip_runtime.h>

typedef short s16x8 __attribute__((ext_vector_type(8)));
typedef float f32x4 __attribute__((ext_vector_type(4)));
typedef unsigned int u32;

#define DEV static __device__ __forceinline__

DEV unsigned short f2bf(float x){
  u32 u = __builtin_bit_cast(u32, x);
  return (unsigned short)((u + 0x7FFFu + ((u >> 16) & 1u)) >> 16);
}
DEV float bf2f(unsigned short h){ u32 u = ((u32)h) << 16; return __builtin_bit_cast(float, u); }
DEV u32 pack2(float a, float b){ return (u32)f2bf(a) | ((u32)f2bf(b) << 16); }

DEV void gld16(const void* g, void* l){
  __builtin_amdgcn_global_load_lds((const __attribute__((address_space(1))) u32*)g,
                                   (__attribute__((address_space(3))) u32*)l, 16, 0, 0);
}

// counted vmcnt wait (T4)
template<int N> DEV void vmwait(){
  static_assert(N>=0 && N<=8, "vmcnt range");
  if constexpr (N==0) asm volatile("s_waitcnt vmcnt(0)" ::: "memory");
  else if constexpr (N==1) asm volatile("s_waitcnt vmcnt(1)" ::: "memory");
  else if constexpr (N==2) asm volatile("s_waitcnt vmcnt(2)" ::: "memory");
  else if constexpr (N==3) asm volatile("s_waitcnt vmcnt(3)" ::: "memory");
  else if constexpr (N==4) asm volatile("s_waitcnt vmcnt(4)" ::: "memory");
  else if constexpr (N==5) asm volatile("s_waitcnt vmcnt(5)" ::: "memory");
  else if constexpr (N==6) asm volatile("s_waitcnt vmcnt(6)" ::: "memory");
  else if constexpr (N==7) asm volatile("s_waitcnt vmcnt(7)" ::: "memory");
  else                     asm volatile("s_waitcnt vmcnt(8)" ::: "memory");
}
DEV void pipebar(){
  __builtin_amdgcn_sched_barrier(0);
  __builtin_amdgcn_s_barrier();
  __builtin_amdgcn_sched_barrier(0);
}

// ------- streaming f32 -> bf16 convert body (4-deep unrolled grid-stride) -------
DEV void cvt_body(const float* __restrict__ src, unsigned short* __restrict__ dst,
                  long n4, int bid, int nblocks){
  long i = (long)bid*256 + threadIdx.x;
  long stride = (long)nblocks*256;
  for (; i + 3*stride < n4; i += 4*stride){
    float4 v0 = ((const float4*)src)[i];
    float4 v1 = ((const float4*)src)[i+stride];
    float4 v2 = ((const float4*)src)[i+2*stride];
    float4 v3 = ((const float4*)src)[i+3*stride];
    int2 p0{(int)pack2(v0.x,v0.y),(int)pack2(v0.z,v0.w)};
    int2 p1{(int)pack2(v1.x,v1.y),(int)pack2(v1.z,v1.w)};
    int2 p2{(int)pack2(v2.x,v2.y),(int)pack2(v2.z,v2.w)};
    int2 p3{(int)pack2(v3.x,v3.y),(int)pack2(v3.z,v3.w)};
    ((int2*)dst)[i] = p0;
    ((int2*)dst)[i+stride] = p1;
    ((int2*)dst)[i+2*stride] = p2;
    ((int2*)dst)[i+3*stride] = p3;
  }
  for (; i < n4; i += stride){
    float4 v = ((const float4*)src)[i];
    int2 p{(int)pack2(v.x,v.y),(int)pack2(v.z,v.w)};
    ((int2*)dst)[i] = p;
  }
}

// ---------------- standalone streaming convert (8 VGPR, no LDS, full occupancy) ----
__global__ void k_cvt(const float* __restrict__ src, unsigned short* __restrict__ dst, long n4){
  cvt_body(src, dst, n4, blockIdx.x, gridDim.x);
}

// ---------------- misc: w1,w2 transpose->bf16 (+) cvt xi ----------------
__global__ __launch_bounds__(256)
void k_misc(const float* __restrict__ w1, const float* __restrict__ w2,
            unsigned short* __restrict__ w1t, unsigned short* __restrict__ w2t,
            const float* __restrict__ xi, unsigned short* __restrict__ xib){
  int bid = blockIdx.x;
  if (bid < 576){
    int idx = bid*256 + threadIdx.x;
    if (idx < 512*256){ int r=idx/256, c=idx%256; w1t[(size_t)c*512 + r] = f2bf(w1[idx]); }
    else { int j = idx - 512*256; if (j < 256*64){ int r=j/64, c=j%64; w2t[(size_t)c*256 + r] = f2bf(w2[j]); } }
  } else {
    cvt_body(xi, xib, (long)8192*512/4, bid-576, 512);
  }
}

// ------- bf16 staging: global_load_lds 16B, swizzle on GLOBAL src (rule 21) -------
// physical slot s of row r holds source k-chunk s ^ SW(r), SW(r)=(r>>RSH)&SLM.
// RSH=1 for 4-slot rows (BK=32) -> read banks split on r&1 (free 2-way);
// RSH=0 for 8-slot rows (BK=64) -> lanes r,r+8 share bank (free 2-way).
template<int ROWS,int BK,int THREADS>
DEV void stage_lds(const unsigned short* __restrict__ src, int row0, int ld,
                   int kk, char* lds, int tid){
  constexpr int SLOTS = BK/8, SLM = SLOTS-1, RPC = 64/SLOTS;
  constexpr int RSH = (SLOTS==4) ? 1 : 0;
  constexpr int NCH = ROWS*BK*2/1024;
  constexpr int NW = THREADS/64, NI = NCH/NW;
  static_assert(NI*NW==NCH, "chunk exact");
  const int lane = tid & 63, wid = tid >> 6;
  #pragma unroll
  for (int i=0;i<NI;i++){
    int c = i*NW + wid;
    int r = c*RPC + lane/SLOTS;
    int s = lane & SLM;
    int ks = s ^ ((r>>RSH)&SLM);
    gld16(src + (size_t)(row0+r)*ld + kk + ks*8, lds + c*1024);
  }
}

// ---------------- pure-bf16 pipelined GEMM body: C = A[M,K] @ Bt[N,K]^T ----------------
// T3+T4: 3 LDS buffers, 2 tiles in flight, counted vmcnt, raw barriers.
template<int BM,int BN,int BK,int WR,int WC,bool PART>
DEV void gemm_body(const unsigned short* __restrict__ A, const unsigned short* __restrict__ B,
                   void* __restrict__ Cp, int lda, int ldb, int ldc, int kchunk,
                   long pstride, char* smem, int bx, int by, int bz)
{
  constexpr int THREADS = WR*WC*64;
  constexpr int ROWB = BK*2, SLOTS = BK/8, SLM = SLOTS-1;
  constexpr int RSH = (SLOTS==4) ? 1 : 0;
  constexpr int TBYTES = (BM+BN)*ROWB;
  constexpr int WM = BM/WR, WN = BN/WC;
  constexpr int FM = WM/16, FN = WN/16, KS = BK/32;
  constexpr int LA = BM*ROWB/1024/(THREADS/64);
  constexpr int LB = BN*ROWB/1024/(THREADS/64);
  constexpr int L  = LA + LB;

  const int tid = threadIdx.x, lane = tid & 63;
  const int wid = tid >> 6, wrr = wid / WC, wcc = wid % WC;
  const int m0 = by * BM, n0 = bx * BN;
  const int kbeg = bz * kchunk, nk = kchunk / BK;

  f32x4 acc[FM][FN];
  f32x4 z4 = {0.f,0.f,0.f,0.f};
  #pragma unroll
  for (int m=0;m<FM;m++)
    #pragma unroll
    for (int n=0;n<FN;n++) acc[m][n] = z4;

  auto stage = [&](int kk, char* buf){
    stage_lds<BM,BK,THREADS>(A, m0, lda, kk, buf, tid);
    stage_lds<BN,BK,THREADS>(B, n0, ldb, kk, buf + BM*ROWB, tid);
  };
  auto compute = [&](const char* buf){
    const char* bA = buf;
    const char* bB = buf + BM*ROWB;
    #pragma unroll
    for (int ks=0;ks<KS;ks++){
      s16x8 av[FM], bv[FN];
      #pragma unroll
      for (int m=0;m<FM;m++){
        int r = wrr*WM + m*16 + (lane&15);
        int s = (ks*4 + (lane>>4)) ^ ((r>>RSH)&SLM);
        av[m] = *(const s16x8*)(bA + r*ROWB + s*16);
      }
      #pragma unroll
      for (int n=0;n<FN;n++){
        int r = wcc*WN + n*16 + (lane&15);
        int s = (ks*4 + (lane>>4)) ^ ((r>>RSH)&SLM);
        bv[n] = *(const s16x8*)(bB + r*ROWB + s*16);
      }
      #pragma unroll
      for (int m=0;m<FM;m++)
        #pragma unroll
        for (int n=0;n<FN;n++)
          acc[m][n] = __builtin_amdgcn_mfma_f32_16x16x32_bf16(av[m], bv[n], acc[m][n], 0, 0, 0);
    }
  };

  char* bc  = smem;
  char* bn_ = smem + TBYTES;
  char* bf_ = smem + 2*TBYTES;

  stage(kbeg, bc);
  stage(kbeg + BK, bn_);

  for (int t=0; t<nk; t++){
    if (t+1 < nk) vmwait<L>();   // tile t landed; t+1's L loads stay in flight
    else          vmwait<0>();
    pipebar();
    if (t+2 < nk) stage(kbeg + (t+2)*BK, bf_);
    compute(bc);
    pipebar();
    char* tmp = bc; bc = bn_; bn_ = bf_; bf_ = tmp;
  }

  // epilogue: C/D layout (verified m89): col=lane&15, row=(lane>>4)*4+reg
  if constexpr (PART) {
    float* Cf = (float*)Cp + (size_t)bz * pstride;
    #pragma unroll
    for (int m=0;m<FM;m++)
      #pragma unroll
      for (int n=0;n<FN;n++)
        #pragma unroll
        for (int r=0;r<4;r++){
          int row = m0 + wrr*WM + m*16 + (lane>>4)*4 + r;
          int col = n0 + wcc*WN + n*16 + (lane&15);
          Cf[(size_t)row*ldc + col] = acc[m][n][r];
        }
  } else {
    unsigned short* Ch = (unsigned short*)Cp;
    #pragma unroll
    for (int m=0;m<FM;m++)
      #pragma unroll
      for (int n=0;n<FN;n++)
        #pragma unroll
        for (int r=0;r<4;r++){
          int row = m0 + wrr*WM + m*16 + (lane>>4)*4 + r;
          int col = n0 + wcc*WN + n*16 + (lane&15);
          Ch[(size_t)row*ldc + col] = f2bf(acc[m][n][r]);
        }
  }
}

// standalone GEMM kernel
template<int BM,int BN,int BK,int WR,int WC,bool PART>
__global__ __launch_bounds__(WR*WC*64, 4)
void k_gemm(const unsigned short* __restrict__ A, const unsigned short* __restrict__ B,
            void* __restrict__ Cp, int lda, int ldb, int ldc, int kchunk, long pstride)
{
  __shared__ char smem[3*(BM+BN)*BK*2];
  gemm_body<BM,BN,BK,WR,WC,PART>(A, B, Cp, lda, ldb, ldc, kchunk, pstride,
                                 smem, blockIdx.x, blockIdx.y, blockIdx.z);
}

// ---------------- h reduce: h = relu(sum_z h_part[z]) -> bf16 ----------------
__global__ void k_hred(const float* __restrict__ hp, unsigned short* __restrict__ h){
  const long N = (long)8192*256/4;           // float4 count
  long i = (long)blockIdx.x*256 + threadIdx.x;
  if (i >= N) return;
  float4 s = ((const float4*)hp)[i];
  #pragma unroll
  for (int z=1; z<8; z++){
    float4 v = ((const float4*)(hp + (size_t)z*8192*256))[i];
    s.x+=v.x; s.y+=v.y; s.z+=v.z; s.w+=v.w;
  }
  int2 p;
  p.x = (int)pack2(fmaxf(s.x,0.f), fmaxf(s.y,0.f));
  p.y = (int)pack2(fmaxf(s.z,0.f), fmaxf(s.w,0.f));
  ((int2*)h)[i] = p;
}

// ---------------- emb finalize: sum e_part -> f32 out, bf16 copy, row sq-sums ------
__global__ void k_emb_fin(const float* __restrict__ ep, float* __restrict__ emb_out,
                          unsigned short* __restrict__ embb, float* __restrict__ sq){
  int idx = blockIdx.x*256 + threadIdx.x;   // 8192*64 threads, 64 lanes == one row
  float v = 0.f;
  #pragma unroll
  for (int z=0; z<8; z++) v += ep[(size_t)z*8192*64 + idx];
  emb_out[idx] = v;
  unsigned short ub = f2bf(v);
  embb[idx] = ub;
  float x = bf2f(ub);
  float s = x*x;
  #pragma unroll
  for (int off=32; off>0; off>>=1) s += __shfl_xor(s, off, 64);
  if ((threadIdx.x & 63)==0) sq[idx>>6] = s;
}

// ---------------- distance softmax (G = emb@emb^T tiles via MFMA) ----------------
template<int PASS>
__global__ __launch_bounds__(256)
void k_dist(const unsigned short* __restrict__ embb, const float* __restrict__ sq,
            float* __restrict__ S, float* __restrict__ out)
{
  constexpr int ROWB = 128, SLM = 7;
  __shared__ char smem[2*128*128];
  char* bufA = smem;
  char* bufB = smem + 128*ROWB;
  const int tid=threadIdx.x, lane=tid&63, wid=tid>>6;
  const int wrr = wid>>1, wcc = wid&1;
  const int i0 = blockIdx.y*128, j0 = blockIdx.x*128;

  #pragma unroll
  for (int i=0;i<4;i++){
    int u = tid + i*256;
    int r = u>>3, c = u&7;
    int byte = r*ROWB + ((c^(r&SLM))*16);
    *(int4*)(bufA+byte) = *(const int4*)(embb + (size_t)(i0+r)*64 + c*8);
    *(int4*)(bufB+byte) = *(const int4*)(embb + (size_t)(j0+r)*64 + c*8);
  }
  __syncthreads();

  f32x4 acc[4][4];
  f32x4 z4 = {0.f,0.f,0.f,0.f};
  #pragma unroll
  for (int m=0;m<4;m++)
    #pragma unroll
    for (int n=0;n<4;n++) acc[m][n]=z4;

  #pragma unroll
  for (int ks=0;ks<2;ks++){
    s16x8 av[4], bv[4];
    #pragma unroll
    for (int m=0;m<4;m++){
      int r = wrr*64 + m*16 + (lane&15);
      int slot = (ks*4 + (lane>>4)) ^ (r&SLM);
      av[m] = *(const s16x8*)(bufA + r*ROWB + slot*16);
    }
    #pragma unroll
    for (int n=0;n<4;n++){
      int r = wcc*64 + n*16 + (lane&15);
      int slot = (ks*4 + (lane>>4)) ^ (r&SLM);
      bv[n] = *(const s16x8*)(bufB + r*ROWB + slot*16);
    }
    #pragma unroll
    for (int m=0;m<4;m++)
      #pragma unroll
      for (int n=0;n<4;n++)
        acc[m][n] = __builtin_amdgcn_mfma_f32_16x16x32_bf16(av[m], bv[n], acc[m][n], 0, 0, 0);
  }

  float sqj[4];
  #pragma unroll
  for (int n=0;n<4;n++) sqj[n] = sq[j0 + wcc*64 + n*16 + (lane&15)];

  #pragma unroll
  for (int m=0;m<4;m++){
    #pragma unroll
    for (int r=0;r<4;r++){
      int row = i0 + wrr*64 + m*16 + (lane>>4)*4 + r;
      float sqi = sq[row];
      if constexpr (PASS==1){
        float v = 0.f;
        #pragma unroll
        for (int n=0;n<4;n++){
          float d = fmaxf(sqi + sqj[n] - 2.f*acc[m][n][r], 0.f);
          v += __expf(-d);
        }
        #pragma unroll
        for (int off=1; off<16; off<<=1) v += __shfl_xor(v, off, 64);
        if ((lane&15)==0) atomicAdd(S+row, v);
      } else {
        float inv = 1.0f / S[row];
        #pragma unroll
        for (int n=0;n<4;n++){
          int col = j0 + wcc*64 + n*16 + (lane&15);
          float d = fmaxf(sqi + sqj[n] - 2.f*acc[m][n][r], 0.f);
          out[(size_t)row*8192 + col] = __expf(-d)*inv + 1e-10f;
        }
      }
    }
  }
}

// ---------------- host launch ----------------
extern "C" void kernel_launch(void* const* d_in, const int* in_sizes, int n_in,
                              void* d_out, int out_size, void* d_ws, size_t ws_size,
                              hipStream_t stream)
{
  const float* xi = (const float*)d_in[0];   // [8192,512]
  const float* F  = (const float*)d_in[1];   // [8192,8192]
  const float* w1 = (const float*)d_in[2];   // [512,256]
  const float* w2 = (const float*)d_in[3];   // [256,64]
  float* out = (float*)d_out;
  float* emb_out = out;                      // 8192*64
  float* recons  = out + (size_t)8192*64;    // 8192*8192

  // F-bf16 lives in the recons region of d_out (scratch until k_dist<2>
  // overwrites every element at the end).
  unsigned short* Fb = (unsigned short*)recons;

  char* ws = (char*)d_ws;
  size_t off = 0;
  auto alloc = [&](size_t bytes)->char*{ char* p = ws + off; off += (bytes + 255) & ~(size_t)255; return p; };
  unsigned short* w1t  = (unsigned short*)alloc((size_t)256*512*2);
  unsigned short* w2t  = (unsigned short*)alloc((size_t)64*256*2);
  unsigned short* xib  = (unsigned short*)alloc((size_t)8192*512*2);
  unsigned short* t1t  = (unsigned short*)alloc((size_t)256*8192*2);
  unsigned short* t2t  = (unsigned short*)alloc((size_t)64*8192*2);
  unsigned short* h    = (unsigned short*)alloc((size_t)8192*256*2);
  unsigned short* embb = (unsigned short*)alloc((size_t)8192*64*2);
  float* sq     = (float*)alloc((size_t)8192*4);
  float* h_part = (float*)alloc((size_t)8*8192*256*4);   // 64 MB
  float* e_part = (float*)alloc((size_t)8*8192*64*4);    // 16 MB
  float* S      = (float*)alloc((size_t)8192*4);

  hipMemsetAsync(S, 0, (size_t)8192*4, stream);

  // misc: {w1,w2 transpose} + {cvt xi} (independent, one launch)
  k_misc<<<dim3(1088),256,0,stream>>>(w1, w2, w1t, w2t, xi, xib);

  // cvt F -> Fb (standalone: 8 VGPR, no LDS, full occupancy -> HBM-saturating)
  k_cvt<<<dim3(2048),256,0,stream>>>(F, Fb, (long)8192*8192/4);

  // G1: t1t[256,8192] = w1t[256,512] @ xib[8192,512]^T
  //     BM=64 -> grid y = 256/64 = 4  (R9 bug: y=2 left rows 128..255 stale)
  k_gemm<64,64,64,2,2,false><<<dim3(128,4,1),256,0,stream>>>(
      w1t, xib, t1t, 512, 512, 8192, 512, 0);

  // G2: h_part[z][8192,256] = Fb @ t1t^T  (BN=256 -> F once; split-K=8, 512 blocks)
  k_gemm<128,256,32,2,4,true><<<dim3(1,64,8),512,0,stream>>>(
      Fb, t1t, h_part, 8192, 8192, 256, 1024, (long)8192*256);

  k_hred<<<dim3(2048),256,0,stream>>>(h_part, h);

  // G3: t2t[64,8192] = w2t[64,256] @ h[8192,256]^T   (256 blocks)
  k_gemm<64,32,64,2,2,false><<<dim3(256,1,1),256,0,stream>>>(
      w2t, h, t2t, 256, 256, 8192, 256, 0);

  // G4: e_part[z][8192,64] = Fb @ t2t^T   (split-K=8, 512 blocks, 512 thr WR=4)
  k_gemm<128,64,64,4,2,true><<<dim3(1,64,8),512,0,stream>>>(
      Fb, t2t, e_part, 8192, 8192, 64, 1024, (long)8192*64);

  k_emb_fin<<<dim3(8192*64/256),256,0,stream>>>(e_part, emb_out, embb, sq);

  k_dist<1><<<dim3(64,64),256,0,stream>>>(embb, sq, S, recons);
  k_dist<2><<<dim3(64,64),256,0,stream>>>(embb, sq, S, recons);
}

// Round 11
// 322.787 us; speedup vs baseline: 1.1455x; 1.1455x over previous
//
#include <hip/hip_runtime.h>

typedef short s16x8 __attribute__((ext_vector_type(8)));
typedef float f32x4 __attribute__((ext_vector_type(4)));
typedef unsigned int u32;

#define DEV static __device__ __forceinline__

DEV unsigned short f2bf(float x){
  u32 u = __builtin_bit_cast(u32, x);
  return (unsigned short)((u + 0x7FFFu + ((u >> 16) & 1u)) >> 16);
}
DEV float bf2f(unsigned short h){ u32 u = ((u32)h) << 16; return __builtin_bit_cast(float, u); }
DEV u32 pack2(float a, float b){ return (u32)f2bf(a) | ((u32)f2bf(b) << 16); }

DEV void gld16(const void* g, void* l){
  __builtin_amdgcn_global_load_lds((const __attribute__((address_space(1))) u32*)g,
                                   (__attribute__((address_space(3))) u32*)l, 16, 0, 0);
}

// counted vmcnt wait (T4)
template<int N> DEV void vmwait(){
  static_assert(N>=0 && N<=8, "vmcnt range");
  if constexpr (N==0) asm volatile("s_waitcnt vmcnt(0)" ::: "memory");
  else if constexpr (N==1) asm volatile("s_waitcnt vmcnt(1)" ::: "memory");
  else if constexpr (N==2) asm volatile("s_waitcnt vmcnt(2)" ::: "memory");
  else if constexpr (N==3) asm volatile("s_waitcnt vmcnt(3)" ::: "memory");
  else if constexpr (N==4) asm volatile("s_waitcnt vmcnt(4)" ::: "memory");
  else if constexpr (N==5) asm volatile("s_waitcnt vmcnt(5)" ::: "memory");
  else if constexpr (N==6) asm volatile("s_waitcnt vmcnt(6)" ::: "memory");
  else if constexpr (N==7) asm volatile("s_waitcnt vmcnt(7)" ::: "memory");
  else                     asm volatile("s_waitcnt vmcnt(8)" ::: "memory");
}
DEV void pipebar(){
  __builtin_amdgcn_sched_barrier(0);
  __builtin_amdgcn_s_barrier();
  __builtin_amdgcn_sched_barrier(0);
}

// ------- streaming f32 -> bf16 convert body (4-deep unrolled grid-stride) -------
DEV void cvt_body(const float* __restrict__ src, unsigned short* __restrict__ dst,
                  long n4, int bid, int nblocks){
  long i = (long)bid*256 + threadIdx.x;
  long stride = (long)nblocks*256;
  for (; i + 3*stride < n4; i += 4*stride){
    float4 v0 = ((const float4*)src)[i];
    float4 v1 = ((const float4*)src)[i+stride];
    float4 v2 = ((const float4*)src)[i+2*stride];
    float4 v3 = ((const float4*)src)[i+3*stride];
    int2 p0{(int)pack2(v0.x,v0.y),(int)pack2(v0.z,v0.w)};
    int2 p1{(int)pack2(v1.x,v1.y),(int)pack2(v1.z,v1.w)};
    int2 p2{(int)pack2(v2.x,v2.y),(int)pack2(v2.z,v2.w)};
    int2 p3{(int)pack2(v3.x,v3.y),(int)pack2(v3.z,v3.w)};
    ((int2*)dst)[i] = p0;
    ((int2*)dst)[i+stride] = p1;
    ((int2*)dst)[i+2*stride] = p2;
    ((int2*)dst)[i+3*stride] = p3;
  }
  for (; i < n4; i += stride){
    float4 v = ((const float4*)src)[i];
    int2 p{(int)pack2(v.x,v.y),(int)pack2(v.z,v.w)};
    ((int2*)dst)[i] = p;
  }
}

// ---------------- fused streaming prep: {w transpose} + {cvt xi} + {cvt F} --------
// all parts are light (no LDS, ~8 VGPR) -> full occupancy everywhere (R8 lesson:
// never fuse streaming work into a heavy-resource kernel).
__global__ __launch_bounds__(256)
void k_stream(const float* __restrict__ w1, const float* __restrict__ w2,
              unsigned short* __restrict__ w1t, unsigned short* __restrict__ w2t,
              const float* __restrict__ xi, unsigned short* __restrict__ xib,
              const float* __restrict__ F, unsigned short* __restrict__ Fb){
  int bid = blockIdx.x;
  if (bid < 576){
    int idx = bid*256 + threadIdx.x;
    if (idx < 512*256){ int r=idx/256, c=idx%256; w1t[(size_t)c*512 + r] = f2bf(w1[idx]); }
    else { int j = idx - 512*256; if (j < 256*64){ int r=j/64, c=j%64; w2t[(size_t)c*256 + r] = f2bf(w2[j]); } }
  } else if (bid < 1088){
    cvt_body(xi, xib, (long)8192*512/4, bid-576, 512);
  } else {
    cvt_body(F, Fb, (long)8192*8192/4, bid-1088, 2048);
  }
}

// ------- bf16 staging: global_load_lds 16B, swizzle on GLOBAL src (rule 21) -------
// physical slot s of row r holds source k-chunk s ^ SW(r), SW(r)=(r>>RSH)&SLM.
template<int ROWS,int BK,int THREADS>
DEV void stage_lds(const unsigned short* __restrict__ src, int row0, int ld,
                   int kk, char* lds, int tid){
  constexpr int SLOTS = BK/8, SLM = SLOTS-1, RPC = 64/SLOTS;
  constexpr int RSH = (SLOTS==4) ? 1 : 0;
  constexpr int NCH = ROWS*BK*2/1024;
  constexpr int NW = THREADS/64, NI = NCH/NW;
  static_assert(NI*NW==NCH, "chunk exact");
  const int lane = tid & 63, wid = tid >> 6;
  #pragma unroll
  for (int i=0;i<NI;i++){
    int c = i*NW + wid;
    int r = c*RPC + lane/SLOTS;
    int s = lane & SLM;
    int ks = s ^ ((r>>RSH)&SLM);
    gld16(src + (size_t)(row0+r)*ld + kk + ks*8, lds + c*1024);
  }
}

// ---------------- pure-bf16 pipelined GEMM: C[M,N] = A[M,K] @ Bt[N,K]^T ----------------
// T3+T4: 3 LDS buffers, 2 tiles in flight, counted vmcnt, raw barriers.
template<int BM,int BN,int BK,int WR,int WC,bool PART>
__global__ __launch_bounds__(WR*WC*64, 4)
void k_gemm(const unsigned short* __restrict__ A, const unsigned short* __restrict__ B,
            void* __restrict__ Cp, int lda, int ldb, int ldc, int kchunk, long pstride)
{
  constexpr int THREADS = WR*WC*64;
  constexpr int ROWB = BK*2, SLOTS = BK/8, SLM = SLOTS-1;
  constexpr int RSH = (SLOTS==4) ? 1 : 0;
  constexpr int TBYTES = (BM+BN)*ROWB;
  constexpr int WM = BM/WR, WN = BN/WC;
  constexpr int FM = WM/16, FN = WN/16, KS = BK/32;
  constexpr int LA = BM*ROWB/1024/(THREADS/64);
  constexpr int LB = BN*ROWB/1024/(THREADS/64);
  constexpr int L  = LA + LB;

  __shared__ char smem[3*TBYTES];

  const int tid = threadIdx.x, lane = tid & 63;
  const int wid = tid >> 6, wrr = wid / WC, wcc = wid % WC;
  const int m0 = blockIdx.y * BM, n0 = blockIdx.x * BN;
  const int kbeg = blockIdx.z * kchunk, nk = kchunk / BK;

  f32x4 acc[FM][FN];
  f32x4 z4 = {0.f,0.f,0.f,0.f};
  #pragma unroll
  for (int m=0;m<FM;m++)
    #pragma unroll
    for (int n=0;n<FN;n++) acc[m][n] = z4;

  auto stage = [&](int kk, char* buf){
    stage_lds<BM,BK,THREADS>(A, m0, lda, kk, buf, tid);
    stage_lds<BN,BK,THREADS>(B, n0, ldb, kk, buf + BM*ROWB, tid);
  };
  auto compute = [&](const char* buf){
    const char* bA = buf;
    const char* bB = buf + BM*ROWB;
    #pragma unroll
    for (int ks=0;ks<KS;ks++){
      s16x8 av[FM], bv[FN];
      #pragma unroll
      for (int m=0;m<FM;m++){
        int r = wrr*WM + m*16 + (lane&15);
        int s = (ks*4 + (lane>>4)) ^ ((r>>RSH)&SLM);
        av[m] = *(const s16x8*)(bA + r*ROWB + s*16);
      }
      #pragma unroll
      for (int n=0;n<FN;n++){
        int r = wcc*WN + n*16 + (lane&15);
        int s = (ks*4 + (lane>>4)) ^ ((r>>RSH)&SLM);
        bv[n] = *(const s16x8*)(bB + r*ROWB + s*16);
      }
      #pragma unroll
      for (int m=0;m<FM;m++)
        #pragma unroll
        for (int n=0;n<FN;n++)
          acc[m][n] = __builtin_amdgcn_mfma_f32_16x16x32_bf16(av[m], bv[n], acc[m][n], 0, 0, 0);
    }
  };

  char* bc  = smem;
  char* bn_ = smem + TBYTES;
  char* bf_ = smem + 2*TBYTES;

  stage(kbeg, bc);
  stage(kbeg + BK, bn_);

  for (int t=0; t<nk; t++){
    if (t+1 < nk) vmwait<L>();   // tile t landed; t+1's L loads stay in flight
    else          vmwait<0>();
    pipebar();
    if (t+2 < nk) stage(kbeg + (t+2)*BK, bf_);
    compute(bc);
    pipebar();
    char* tmp = bc; bc = bn_; bn_ = bf_; bf_ = tmp;
  }

  // epilogue: C/D layout (verified m89): col=lane&15, row=(lane>>4)*4+reg
  if constexpr (PART) {
    float* Cf = (float*)Cp + (size_t)blockIdx.z * pstride;
    #pragma unroll
    for (int m=0;m<FM;m++)
      #pragma unroll
      for (int n=0;n<FN;n++)
        #pragma unroll
        for (int r=0;r<4;r++){
          int row = m0 + wrr*WM + m*16 + (lane>>4)*4 + r;
          int col = n0 + wcc*WN + n*16 + (lane&15);
          Cf[(size_t)row*ldc + col] = acc[m][n][r];
        }
  } else {
    unsigned short* Ch = (unsigned short*)Cp;
    #pragma unroll
    for (int m=0;m<FM;m++)
      #pragma unroll
      for (int n=0;n<FN;n++)
        #pragma unroll
        for (int r=0;r<4;r++){
          int row = m0 + wrr*WM + m*16 + (lane>>4)*4 + r;
          int col = n0 + wcc*WN + n*16 + (lane&15);
          Ch[(size_t)row*ldc + col] = f2bf(acc[m][n][r]);
        }
  }
}

// ---------------- h reduce: h = relu(sum_z h_part[z]) -> bf16 ----------------
__global__ void k_hred(const float* __restrict__ hp, unsigned short* __restrict__ h){
  const long N = (long)8192*256/4;           // float4 count
  long i = (long)blockIdx.x*256 + threadIdx.x;
  if (i >= N) return;
  float4 s = ((const float4*)hp)[i];
  #pragma unroll
  for (int z=1; z<8; z++){
    float4 v = ((const float4*)(hp + (size_t)z*8192*256))[i];
    s.x+=v.x; s.y+=v.y; s.z+=v.z; s.w+=v.w;
  }
  int2 p;
  p.x = (int)pack2(fmaxf(s.x,0.f), fmaxf(s.y,0.f));
  p.y = (int)pack2(fmaxf(s.z,0.f), fmaxf(s.w,0.f));
  ((int2*)h)[i] = p;
}

// ---------------- emb finalize: sum e_part -> f32 out, bf16 copy, row sq-sums ------
__global__ void k_emb_fin(const float* __restrict__ ep, float* __restrict__ emb_out,
                          unsigned short* __restrict__ embb, float* __restrict__ sq){
  int idx = blockIdx.x*256 + threadIdx.x;   // 8192*64 threads, 64 lanes == one row
  float v = 0.f;
  #pragma unroll
  for (int z=0; z<8; z++) v += ep[(size_t)z*8192*64 + idx];
  emb_out[idx] = v;
  unsigned short ub = f2bf(v);
  embb[idx] = ub;
  float x = bf2f(ub);
  float s = x*x;
  #pragma unroll
  for (int off=32; off>0; off>>=1) s += __shfl_xor(s, off, 64);
  if ((threadIdx.x & 63)==0) sq[idx>>6] = s;
}

// ---------------- distance softmax (G = emb@emb^T tiles via MFMA) ----------------
// PASS1: per-block LDS row-sum of exp(-d) -> one coalesced store per row into
//        Spart[jblk][8192] (NO global atomics; was 512 serialized RMW/address).
// PASS2: out = exp(-d)/S_i + 1e-10
template<int PASS>
__global__ __launch_bounds__(256)
void k_dist(const unsigned short* __restrict__ embb, const float* __restrict__ sq,
            float* __restrict__ Spart, const float* __restrict__ S, float* __restrict__ out)
{
  constexpr int ROWB = 128, SLM = 7;
  __shared__ char smem[2*128*128];
  __shared__ float ldsS[128];
  char* bufA = smem;
  char* bufB = smem + 128*ROWB;
  const int tid=threadIdx.x, lane=tid&63, wid=tid>>6;
  const int wrr = wid>>1, wcc = wid&1;
  const int i0 = blockIdx.y*128, j0 = blockIdx.x*128;

  if (PASS==1 && tid < 128) ldsS[tid] = 0.f;

  #pragma unroll
  for (int i=0;i<4;i++){
    int u = tid + i*256;
    int r = u>>3, c = u&7;
    int byte = r*ROWB + ((c^(r&SLM))*16);
    *(int4*)(bufA+byte) = *(const int4*)(embb + (size_t)(i0+r)*64 + c*8);
    *(int4*)(bufB+byte) = *(const int4*)(embb + (size_t)(j0+r)*64 + c*8);
  }
  __syncthreads();

  f32x4 acc[4][4];
  f32x4 z4 = {0.f,0.f,0.f,0.f};
  #pragma unroll
  for (int m=0;m<4;m++)
    #pragma unroll
    for (int n=0;n<4;n++) acc[m][n]=z4;

  #pragma unroll
  for (int ks=0;ks<2;ks++){
    s16x8 av[4], bv[4];
    #pragma unroll
    for (int m=0;m<4;m++){
      int r = wrr*64 + m*16 + (lane&15);
      int slot = (ks*4 + (lane>>4)) ^ (r&SLM);
      av[m] = *(const s16x8*)(bufA + r*ROWB + slot*16);
    }
    #pragma unroll
    for (int n=0;n<4;n++){
      int r = wcc*64 + n*16 + (lane&15);
      int slot = (ks*4 + (lane>>4)) ^ (r&SLM);
      bv[n] = *(const s16x8*)(bufB + r*ROWB + slot*16);
    }
    #pragma unroll
    for (int m=0;m<4;m++)
      #pragma unroll
      for (int n=0;n<4;n++)
        acc[m][n] = __builtin_amdgcn_mfma_f32_16x16x32_bf16(av[m], bv[n], acc[m][n], 0, 0, 0);
  }

  float sqj[4];
  #pragma unroll
  for (int n=0;n<4;n++) sqj[n] = sq[j0 + wcc*64 + n*16 + (lane&15)];

  #pragma unroll
  for (int m=0;m<4;m++){
    #pragma unroll
    for (int r=0;r<4;r++){
      int rloc = wrr*64 + m*16 + (lane>>4)*4 + r;
      int row  = i0 + rloc;
      float sqi = sq[row];
      if constexpr (PASS==1){
        float v = 0.f;
        #pragma unroll
        for (int n=0;n<4;n++){
          float d = fmaxf(sqi + sqj[n] - 2.f*acc[m][n][r], 0.f);
          v += __expf(-d);
        }
        #pragma unroll
        for (int off=1; off<16; off<<=1) v += __shfl_xor(v, off, 64);
        if ((lane&15)==0) atomicAdd(&ldsS[rloc], v);   // LDS atomic (2-way)
      } else {
        float inv = 1.0f / S[row];
        #pragma unroll
        for (int n=0;n<4;n++){
          int col = j0 + wcc*64 + n*16 + (lane&15);
          float d = fmaxf(sqi + sqj[n] - 2.f*acc[m][n][r], 0.f);
          out[(size_t)row*8192 + col] = __expf(-d)*inv + 1e-10f;
        }
      }
    }
  }

  if constexpr (PASS==1){
    __syncthreads();
    if (tid < 128) Spart[(size_t)blockIdx.x*8192 + i0 + tid] = ldsS[tid];
  }
}

// ---------------- S reduce: S[i] = sum_b Spart[b][i] ----------------
__global__ void k_sred(const float* __restrict__ Spart, float* __restrict__ S){
  int i = blockIdx.x*256 + threadIdx.x;   // 8192 threads
  float v = 0.f;
  #pragma unroll
  for (int b=0; b<64; b++) v += Spart[(size_t)b*8192 + i];
  S[i] = v;
}

// ---------------- host launch ----------------
extern "C" void kernel_launch(void* const* d_in, const int* in_sizes, int n_in,
                              void* d_out, int out_size, void* d_ws, size_t ws_size,
                              hipStream_t stream)
{
  const float* xi = (const float*)d_in[0];   // [8192,512]
  const float* F  = (const float*)d_in[1];   // [8192,8192]
  const float* w1 = (const float*)d_in[2];   // [512,256]
  const float* w2 = (const float*)d_in[3];   // [256,64]
  float* out = (float*)d_out;
  float* emb_out = out;                      // 8192*64
  float* recons  = out + (size_t)8192*64;    // 8192*8192

  // F-bf16 lives in the recons region of d_out (scratch until k_dist<2>
  // overwrites every element at the end).
  unsigned short* Fb = (unsigned short*)recons;

  char* ws = (char*)d_ws;
  size_t off = 0;
  auto alloc = [&](size_t bytes)->char*{ char* p = ws + off; off += (bytes + 255) & ~(size_t)255; return p; };
  unsigned short* w1t  = (unsigned short*)alloc((size_t)256*512*2);
  unsigned short* w2t  = (unsigned short*)alloc((size_t)64*256*2);
  unsigned short* xib  = (unsigned short*)alloc((size_t)8192*512*2);
  unsigned short* t1t  = (unsigned short*)alloc((size_t)256*8192*2);
  unsigned short* t2t  = (unsigned short*)alloc((size_t)64*8192*2);
  unsigned short* h    = (unsigned short*)alloc((size_t)8192*256*2);
  unsigned short* embb = (unsigned short*)alloc((size_t)8192*64*2);
  float* sq     = (float*)alloc((size_t)8192*4);
  float* h_part = (float*)alloc((size_t)8*8192*256*4);   // 64 MB
  float* e_part = (float*)alloc((size_t)8*8192*64*4);    // 16 MB
  float* Spart  = (float*)alloc((size_t)64*8192*4);      // 2 MB
  float* S      = (float*)alloc((size_t)8192*4);

  // fused streaming prep: w transpose + cvt xi + cvt F (one launch, light kernel)
  k_stream<<<dim3(3136),256,0,stream>>>(w1, w2, w1t, w2t, xi, xib, F, Fb);

  // G1: t1t[256,8192] = w1t[256,512] @ xib^T   (R7 config)
  k_gemm<128,64,64,2,2,false><<<dim3(128,2,1),256,0,stream>>>(
      w1t, xib, t1t, 512, 512, 8192, 512, 0);

  // G2: h_part[z][8192,256] = Fb @ t1t^T  (BN=256 -> F once; split-K=8, 512 blocks)
  k_gemm<128,256,32,2,4,true><<<dim3(1,64,8),512,0,stream>>>(
      Fb, t1t, h_part, 8192, 8192, 256, 1024, (long)8192*256);

  k_hred<<<dim3(2048),256,0,stream>>>(h_part, h);

  // G3: t2t[64,8192] = w2t[64,256] @ h^T   (256 blocks)
  k_gemm<64,32,64,2,2,false><<<dim3(256,1,1),256,0,stream>>>(
      w2t, h, t2t, 256, 256, 8192, 256, 0);

  // G4: e_part[z][8192,64] = Fb @ t2t^T   (split-K=8, 512 blocks; R7 config)
  k_gemm<128,64,64,2,2,true><<<dim3(1,64,8),256,0,stream>>>(
      Fb, t2t, e_part, 8192, 8192, 64, 1024, (long)8192*64);

  k_emb_fin<<<dim3(8192*64/256),256,0,stream>>>(e_part, emb_out, embb, sq);

  k_dist<1><<<dim3(64,64),256,0,stream>>>(embb, sq, Spart, nullptr, recons);
  k_sred<<<dim3(32),256,0,stream>>>(Spart, S);
  k_dist<2><<<dim3(64,64),256,0,stream>>>(embb, sq, nullptr, S, recons);
}